// Round 2
// baseline (235.474 us; speedup 1.0000x reference)
//
#include <hip/hip_runtime.h>

typedef short short8 __attribute__((ext_vector_type(8)));
typedef _Float16 half8 __attribute__((ext_vector_type(8)));
typedef _Float16 half2v __attribute__((ext_vector_type(2)));
typedef float floatx4 __attribute__((ext_vector_type(4)));

extern "C" __device__ _Float16 __ocml_exp2_f16(_Float16);

#define B_   8
#define N_   2048
#define FIN_ 64
#define H_   4
#define D_   32
#define HD_  128
#define ALPHA_ 0.2f
#define LOG2E_ 1.4426950408889634f

// ws layout (bytes):
//   WhF  f16 [B][H][64 chunk][2 dhalf][64 lane][8] @ 0      (4 MB)  frag-contiguous
//   src  fp32 [B][H][N] (x log2e)                  @ 4 MB   (256 KB)
//   dstb f16 [B][H][N] (x log2e)                   @ 4.25MB (128 KB)

// ---- prep: Wh = h@W; WhF fragment-layout f16, src/dst (x log2e) -------------
__global__ __launch_bounds__(256) void gat_prep4(
    const float* __restrict__ h, const float* __restrict__ W, const float* __restrict__ a,
    unsigned short* __restrict__ WhF, float* __restrict__ src, unsigned short* __restrict__ dstb)
{
    __shared__ float Ws[FIN_][HD_];
    __shared__ float hsT[FIN_][36];
    int bx = blockIdx.x;
    int b = bx >> 6;
    int n0 = (bx & 63) * 32;            // 32 graph nodes (j) per block
    int tid = threadIdx.x;

    #pragma unroll
    for (int it = 0; it < 8; ++it) {
        int idx = it * 256 + tid;
        int k = idx >> 5, c4 = (idx & 31) << 2;
        *(float4*)&Ws[k][c4] = *(const float4*)&W[k * HD_ + c4];
    }
    #pragma unroll
    for (int it = 0; it < 8; ++it) {
        int idx = it * 256 + tid;
        int r = idx >> 6, k = idx & 63;
        hsT[k][r] = h[((size_t)b * N_ + n0 + r) * FIN_ + k];
    }
    __syncthreads();

    int c = tid & 127;                  // output column = h*32+d
    int rq = tid >> 7;                  // 16-row half
    int hh = c >> 5, d = c & 31;
    float acc[16];
    #pragma unroll
    for (int r = 0; r < 16; ++r) acc[r] = 0.f;
    for (int k = 0; k < FIN_; ++k) {
        float wv = Ws[k][c];
        float4 h0 = *(const float4*)&hsT[k][rq * 16];
        float4 h1 = *(const float4*)&hsT[k][rq * 16 + 4];
        float4 h2 = *(const float4*)&hsT[k][rq * 16 + 8];
        float4 h3 = *(const float4*)&hsT[k][rq * 16 + 12];
        acc[0]  += h0.x * wv; acc[1]  += h0.y * wv; acc[2]  += h0.z * wv; acc[3]  += h0.w * wv;
        acc[4]  += h1.x * wv; acc[5]  += h1.y * wv; acc[6]  += h1.z * wv; acc[7]  += h1.w * wv;
        acc[8]  += h2.x * wv; acc[9]  += h2.y * wv; acc[10] += h2.z * wv; acc[11] += h2.w * wv;
        acc[12] += h3.x * wv; acc[13] += h3.y * wv; acc[14] += h3.z * wv; acc[15] += h3.w * wv;
    }

    // FragB write (f16): Wh[j=n0+rq*16+r][col c] -> WhF[b][hh][it][dhalf][g*16+n][e]
    {
        int half = d >> 4, n = d & 15;
        int j0 = n0 + rq * 16;
        int it0 = j0 >> 5;
        int g0 = (j0 >> 3) & 3;         // 0 or 2; spans g0, g0+1
        #pragma unroll
        for (int rr = 0; rr < 2; ++rr) {
            __attribute__((aligned(16))) unsigned pk4[4];
            #pragma unroll
            for (int q = 0; q < 4; ++q)
                pk4[q] = __builtin_bit_cast(unsigned,
                    __builtin_amdgcn_cvt_pkrtz(acc[rr * 8 + 2 * q], acc[rr * 8 + 2 * q + 1]));
            size_t fi = ((((size_t)b * H_ + hh) * 64 + it0) * 2 + half) * 64
                        + (size_t)(g0 + rr) * 16 + n;
            *(uint4*)&WhF[fi * 8] = *(uint4*)pk4;
        }
    }

    float a1v = a[hh * 64 + d];
    float a2v = a[hh * 64 + 32 + d];
    #pragma unroll
    for (int r = 0; r < 16; ++r) {
        float s1 = acc[r] * a1v;
        float s2 = acc[r] * a2v;
        #pragma unroll
        for (int off = 16; off >= 1; off >>= 1) {
            s1 += __shfl_xor(s1, off, 32);
            s2 += __shfl_xor(s2, off, 32);
        }
        if (d == 0) {
            int n = n0 + rq * 16 + r;
            src[(b * H_ + hh) * N_ + n] = s1 * LOG2E_;
            _Float16 hv = (_Float16)(s2 * LOG2E_);
            dstb[(b * H_ + hh) * N_ + n] = __builtin_bit_cast(unsigned short, hv);
        }
    }
}

// ------ main: 32-i blocks, 2 A-tiles per wave share B-frag/dv/adj loads ------
__global__ __launch_bounds__(256, 2) void gat_main13(
    const int* __restrict__ adj, const unsigned short* __restrict__ WhF,
    const float* __restrict__ src, const unsigned short* __restrict__ dstb,
    float* __restrict__ out)
{
    __shared__ unsigned short dsts[H_ * N_];   // 16 KB (all j, f16)
    __shared__ unsigned adjW[32][70];          // stride 70: bank-spread + 8B-aligned rows

    int bx = blockIdx.x;
    int b  = bx >> 6;
    int i0 = (bx & 63) * 32;
    int tid = threadIdx.x;
    int wv = tid >> 6, l = tid & 63;

    #pragma unroll
    for (int it = 0; it < 4; ++it) {           // dst: 8192 f16 = 1024 uint4
        int idx = it * 256 + tid;
        int hh = idx >> 8, off = (idx & 255) * 8;
        *(uint4*)&dsts[hh * N_ + off] =
            *(const uint4*)&dstb[(size_t)(b * H_ + hh) * N_ + off];
    }

    // adj staging: wave wv owns rows wv*8..+7; ballot packs 64->u64
    const int* adjBase = adj + ((size_t)(b * N_ + i0 + wv * 8)) * N_ + l;

    int vals[32];                              // in-flight group: 8 rows x 4 chunks
    #pragma unroll
    for (int rr = 0; rr < 8; ++rr)
        #pragma unroll
        for (int cc = 0; cc < 4; ++cc)
            vals[rr * 4 + cc] = adjBase[rr * N_ + cc * 64];

    int h = wv, g = l >> 4, m = l & 15;
    int g8 = g << 3;
    _Float16 svA = (_Float16)src[(b * H_ + h) * N_ + i0 + m];
    _Float16 svB = (_Float16)src[(b * H_ + h) * N_ + i0 + 16 + m];
    half2v s2A; s2A[0] = svA; s2A[1] = svA;
    half2v s2B; s2B[0] = svB; s2B[1] = svB;
    const _Float16 alf = (_Float16)0.2f;
    // fragment-contiguous B: chunk c at offset c*1024 shorts
    const unsigned short* WhB =
        WhF + ((size_t)(b * H_ + h) * 64) * 1024 + l * 8;
    const unsigned short* dstH = &dsts[h * N_];

    short8 onesS;
    #pragma unroll
    for (int q = 0; q < 8; ++q) onesS[q] = (short)0x3C00;  // f16 1.0
    half8 ones = __builtin_bit_cast(half8, onesS);

    floatx4 acc0A = {0.f, 0.f, 0.f, 0.f};
    floatx4 acc1A = {0.f, 0.f, 0.f, 0.f};
    floatx4 acc2A = {0.f, 0.f, 0.f, 0.f};
    floatx4 acc0B = {0.f, 0.f, 0.f, 0.f};
    floatx4 acc1B = {0.f, 0.f, 0.f, 0.f};
    floatx4 acc2B = {0.f, 0.f, 0.f, 0.f};

    short8 bf0_c = *(const short8*)&WhB[0];    // chunk 0, dhalf 0
    short8 bf1_c = *(const short8*)&WhB[512];  // chunk 0, dhalf 1
    uint4 dv_c;                                // valid after first barrier

    for (int q = 0; q < 8; ++q) {
        // ---- ballot group q into LDS (loads already in flight)
        #pragma unroll
        for (int rr = 0; rr < 8; ++rr)
            #pragma unroll
            for (int cc = 0; cc < 4; ++cc) {
                unsigned long long mk = __ballot(vals[rr * 4 + cc] != 0);
                if (l == 0)
                    *(unsigned long long*)&adjW[wv * 8 + rr][2 * (q * 4 + cc)] = mk;
            }
        __syncthreads();                        // staging q visible to all waves
        if (q == 0) dv_c = *(const uint4*)&dstH[g8];

        // ---- issue group q+1 adj loads (hidden behind compute below)
        if (q < 7) {
            #pragma unroll
            for (int rr = 0; rr < 8; ++rr)
                #pragma unroll
                for (int cc = 0; cc < 4; ++cc)
                    vals[rr * 4 + cc] = adjBase[rr * N_ + (q + 1) * 256 + cc * 64];
        }

        // ---- compute 8 MFMA K-chunks of group q (j in [q*256, q*256+256))
        for (int jj = 0; jj < 8; ++jj) {
            int it = q * 8 + jj;
            int fn = (it + 1) * 1024;           // next chunk (it=63: in-ws overread)
            short8 bf0_n = *(const short8*)&WhB[fn];
            short8 bf1_n = *(const short8*)&WhB[fn + 512];
            int j0n = ((it + 1) << 5) + g8;
            uint4  dv_n  = *(const uint4*)&dstH[(j0n < N_) ? j0n : g8];

            unsigned shA = adjW[m][it] >> g8;       // tile A row bits
            unsigned shB = adjW[m + 16][it] >> g8;  // tile B row bits
            const unsigned* du = (const unsigned*)&dv_c;

            // ---- tile A (rows i0..i0+15)
            {
                __attribute__((aligned(16))) unsigned pk[4];
                #pragma unroll
                for (int c2 = 0; c2 < 4; ++c2) {
                    half2v d2 = __builtin_bit_cast(half2v, du[c2]);
                    half2v e2 = s2A + d2;                           // v_pk_add_f16
                    half2v t2 = e2 * alf;                           // v_pk_mul_f16
                    e2 = __builtin_elementwise_max(e2, t2);         // v_pk_max_f16
                    half2v x2;
                    x2[0] = __ocml_exp2_f16(e2[0]);
                    x2[1] = __ocml_exp2_f16(e2[1]);
                    unsigned mk = ((((shA >> (2 * c2 + 1)) & 1u) << 16)
                                   | ((shA >> (2 * c2)) & 1u)) * 0x3C00u;
                    x2 = x2 * __builtin_bit_cast(half2v, mk);
                    pk[c2] = __builtin_bit_cast(unsigned, x2);
                }
                half8 af = __builtin_bit_cast(half8, *(uint4*)pk);
                acc0A = __builtin_amdgcn_mfma_f32_16x16x32_f16(
                            af, __builtin_bit_cast(half8, bf0_c), acc0A, 0, 0, 0);
                acc1A = __builtin_amdgcn_mfma_f32_16x16x32_f16(
                            af, __builtin_bit_cast(half8, bf1_c), acc1A, 0, 0, 0);
                acc2A = __builtin_amdgcn_mfma_f32_16x16x32_f16(af, ones, acc2A, 0, 0, 0);
            }
            // ---- tile B (rows i0+16..i0+31), same bf/dv loads
            {
                __attribute__((aligned(16))) unsigned pk[4];
                #pragma unroll
                for (int c2 = 0; c2 < 4; ++c2) {
                    half2v d2 = __builtin_bit_cast(half2v, du[c2]);
                    half2v e2 = s2B + d2;
                    half2v t2 = e2 * alf;
                    e2 = __builtin_elementwise_max(e2, t2);
                    half2v x2;
                    x2[0] = __ocml_exp2_f16(e2[0]);
                    x2[1] = __ocml_exp2_f16(e2[1]);
                    unsigned mk = ((((shB >> (2 * c2 + 1)) & 1u) << 16)
                                   | ((shB >> (2 * c2)) & 1u)) * 0x3C00u;
                    x2 = x2 * __builtin_bit_cast(half2v, mk);
                    pk[c2] = __builtin_bit_cast(unsigned, x2);
                }
                half8 af = __builtin_bit_cast(half8, *(uint4*)pk);
                acc0B = __builtin_amdgcn_mfma_f32_16x16x32_f16(
                            af, __builtin_bit_cast(half8, bf0_c), acc0B, 0, 0, 0);
                acc1B = __builtin_amdgcn_mfma_f32_16x16x32_f16(
                            af, __builtin_bit_cast(half8, bf1_c), acc1B, 0, 0, 0);
                acc2B = __builtin_amdgcn_mfma_f32_16x16x32_f16(af, ones, acc2B, 0, 0, 0);
            }
            bf0_c = bf0_n; bf1_c = bf1_n; dv_c = dv_n;
        }
    }

    // in-register finalize (C/D: col=m, row=g*4+r)
    #pragma unroll
    for (int r = 0; r < 4; ++r) {
        float invA = 1.f / acc2A[r];
        size_t oA = ((size_t)b * N_ + i0 + g * 4 + r) * HD_ + h * 32 + m;
        out[oA]      = acc0A[r] * invA;
        out[oA + 16] = acc1A[r] * invA;
        float invB = 1.f / acc2B[r];
        size_t oB = ((size_t)b * N_ + i0 + 16 + g * 4 + r) * HD_ + h * 32 + m;
        out[oB]      = acc0B[r] * invB;
        out[oB + 16] = acc1B[r] * invB;
    }
}

extern "C" void kernel_launch(void* const* d_in, const int* in_sizes, int n_in,
                              void* d_out, int out_size, void* d_ws, size_t ws_size,
                              hipStream_t stream) {
    const float* h   = (const float*)d_in[0];
    const int*   adj = (const int*)d_in[1];
    const float* W   = (const float*)d_in[2];
    const float* a   = (const float*)d_in[3];
    float* out = (float*)d_out;

    unsigned short* WhF  = (unsigned short*)d_ws;
    float*          src  = (float*)((char*)d_ws + 4u * 1024 * 1024);
    unsigned short* dstb = (unsigned short*)((char*)d_ws + 4u * 1024 * 1024 + 256u * 1024);

    gat_prep4<<<B_ * (N_ / 32), 256, 0, stream>>>(h, W, a, WhF, src, dstb);
    gat_main13<<<B_ * (N_ / 32), 256, 0, stream>>>(adj, WhF, src, dstb, out);
}

// Round 3
// 218.943 us; speedup vs baseline: 1.0755x; 1.0755x over previous
//
#include <hip/hip_runtime.h>

typedef short short8 __attribute__((ext_vector_type(8)));
typedef _Float16 half8 __attribute__((ext_vector_type(8)));
typedef _Float16 half2v __attribute__((ext_vector_type(2)));
typedef float floatx4 __attribute__((ext_vector_type(4)));

extern "C" __device__ _Float16 __ocml_exp2_f16(_Float16);

#define B_   8
#define N_   2048
#define FIN_ 64
#define H_   4
#define D_   32
#define HD_  128
#define ALPHA_ 0.2f
#define LOG2E_ 1.4426950408889634f

// ws layout (bytes):
//   WhF  f16 [B][H][64 chunk][2 dhalf][64 lane][8] @ 0      (4 MB)  frag-contiguous
//   src  fp32 [B][H][N] (x log2e)                  @ 4 MB   (256 KB)
//   dstb f16 [B][H][N] (x log2e)                   @ 4.25MB (128 KB)

// ---- prep: Wh = h@W; WhF fragment-layout f16, src/dst (x log2e) -------------
__global__ __launch_bounds__(256) void gat_prep4(
    const float* __restrict__ h, const float* __restrict__ W, const float* __restrict__ a,
    unsigned short* __restrict__ WhF, float* __restrict__ src, unsigned short* __restrict__ dstb)
{
    __shared__ float Ws[FIN_][HD_];
    __shared__ float hsT[FIN_][36];
    int bx = blockIdx.x;
    int b = bx >> 6;
    int n0 = (bx & 63) * 32;            // 32 graph nodes (j) per block
    int tid = threadIdx.x;

    #pragma unroll
    for (int it = 0; it < 8; ++it) {
        int idx = it * 256 + tid;
        int k = idx >> 5, c4 = (idx & 31) << 2;
        *(float4*)&Ws[k][c4] = *(const float4*)&W[k * HD_ + c4];
    }
    #pragma unroll
    for (int it = 0; it < 8; ++it) {
        int idx = it * 256 + tid;
        int r = idx >> 6, k = idx & 63;
        hsT[k][r] = h[((size_t)b * N_ + n0 + r) * FIN_ + k];
    }
    __syncthreads();

    int c = tid & 127;                  // output column = h*32+d
    int rq = tid >> 7;                  // 16-row half
    int hh = c >> 5, d = c & 31;
    float acc[16];
    #pragma unroll
    for (int r = 0; r < 16; ++r) acc[r] = 0.f;
    for (int k = 0; k < FIN_; ++k) {
        float wv = Ws[k][c];
        float4 h0 = *(const float4*)&hsT[k][rq * 16];
        float4 h1 = *(const float4*)&hsT[k][rq * 16 + 4];
        float4 h2 = *(const float4*)&hsT[k][rq * 16 + 8];
        float4 h3 = *(const float4*)&hsT[k][rq * 16 + 12];
        acc[0]  += h0.x * wv; acc[1]  += h0.y * wv; acc[2]  += h0.z * wv; acc[3]  += h0.w * wv;
        acc[4]  += h1.x * wv; acc[5]  += h1.y * wv; acc[6]  += h1.z * wv; acc[7]  += h1.w * wv;
        acc[8]  += h2.x * wv; acc[9]  += h2.y * wv; acc[10] += h2.z * wv; acc[11] += h2.w * wv;
        acc[12] += h3.x * wv; acc[13] += h3.y * wv; acc[14] += h3.z * wv; acc[15] += h3.w * wv;
    }

    // FragB write (f16): Wh[j=n0+rq*16+r][col c] -> WhF[b][hh][it][dhalf][g*16+n][e]
    {
        int half = d >> 4, n = d & 15;
        int j0 = n0 + rq * 16;
        int it0 = j0 >> 5;
        int g0 = (j0 >> 3) & 3;         // 0 or 2; spans g0, g0+1
        #pragma unroll
        for (int rr = 0; rr < 2; ++rr) {
            __attribute__((aligned(16))) unsigned pk4[4];
            #pragma unroll
            for (int q = 0; q < 4; ++q)
                pk4[q] = __builtin_bit_cast(unsigned,
                    __builtin_amdgcn_cvt_pkrtz(acc[rr * 8 + 2 * q], acc[rr * 8 + 2 * q + 1]));
            size_t fi = ((((size_t)b * H_ + hh) * 64 + it0) * 2 + half) * 64
                        + (size_t)(g0 + rr) * 16 + n;
            *(uint4*)&WhF[fi * 8] = *(uint4*)pk4;
        }
    }

    float a1v = a[hh * 64 + d];
    float a2v = a[hh * 64 + 32 + d];
    #pragma unroll
    for (int r = 0; r < 16; ++r) {
        float s1 = acc[r] * a1v;
        float s2 = acc[r] * a2v;
        #pragma unroll
        for (int off = 16; off >= 1; off >>= 1) {
            s1 += __shfl_xor(s1, off, 32);
            s2 += __shfl_xor(s2, off, 32);
        }
        if (d == 0) {
            int n = n0 + rq * 16 + r;
            src[(b * H_ + hh) * N_ + n] = s1 * LOG2E_;
            _Float16 hv = (_Float16)(s2 * LOG2E_);
            dstb[(b * H_ + hh) * N_ + n] = __builtin_bit_cast(unsigned short, hv);
        }
    }
}

// ------ main: 16-i blocks, per-group sh preload, depth-2 bf/dv prefetch ------
__global__ __launch_bounds__(256, 4) void gat_main14(
    const int* __restrict__ adj, const unsigned short* __restrict__ WhF,
    const float* __restrict__ src, const unsigned short* __restrict__ dstb,
    float* __restrict__ out)
{
    __shared__ unsigned short dsts[H_ * N_];   // 16 KB (all j, f16)
    __shared__ unsigned adjW[16][72];          // stride 72 words: rows 16B-aligned

    int bx = blockIdx.x;
    int b  = bx >> 7;
    int i0 = (bx & 127) * 16;
    int tid = threadIdx.x;
    int wv = tid >> 6, l = tid & 63;

    #pragma unroll
    for (int it = 0; it < 4; ++it) {           // dst: 8192 f16 = 1024 uint4
        int idx = it * 256 + tid;
        int hh = idx >> 8, off = (idx & 255) * 8;
        *(uint4*)&dsts[hh * N_ + off] =
            *(const uint4*)&dstb[(size_t)(b * H_ + hh) * N_ + off];
    }

    // adj staging: wave wv owns rows wv*4..+3; ballot packs 64->u64
    const int* adjBase = adj + ((size_t)(b * N_ + i0 + wv * 4)) * N_ + l;

    int vals[16];                              // in-flight group: 4 rows x 4 chunks
    #pragma unroll
    for (int rr = 0; rr < 4; ++rr)
        #pragma unroll
        for (int cc = 0; cc < 4; ++cc)
            vals[rr * 4 + cc] = adjBase[rr * N_ + cc * 64];

    int h = wv, g = l >> 4, m = l & 15;
    int g8 = g << 3;
    _Float16 sv = (_Float16)src[(b * H_ + h) * N_ + i0 + m];
    half2v s2; s2[0] = sv; s2[1] = sv;
    const _Float16 alf = (_Float16)0.2f;
    // fragment-contiguous B: chunk c at offset c*1024 shorts
    const unsigned short* WhB =
        WhF + ((size_t)(b * H_ + h) * 64) * 1024 + l * 8;
    const unsigned short* dstH = &dsts[h * N_];

    short8 onesS;
    #pragma unroll
    for (int q = 0; q < 8; ++q) onesS[q] = (short)0x3C00;  // f16 1.0
    half8 ones = __builtin_bit_cast(half8, onesS);

    floatx4 acc0 = {0.f, 0.f, 0.f, 0.f};
    floatx4 acc1 = {0.f, 0.f, 0.f, 0.f};
    floatx4 acc2 = {0.f, 0.f, 0.f, 0.f};

    // depth-2 B-fragment prefetch (chunks 0 and 1 in flight before loop)
    short8 bf0_a = *(const short8*)&WhB[0];
    short8 bf1_a = *(const short8*)&WhB[512];
    short8 bf0_b = *(const short8*)&WhB[1024];
    short8 bf1_b = *(const short8*)&WhB[1536];
    uint4 dv_a, dv_b;                          // valid after first barrier

    for (int q = 0; q < 8; ++q) {
        // ---- ballot group q into LDS (loads already in flight)
        #pragma unroll
        for (int rr = 0; rr < 4; ++rr)
            #pragma unroll
            for (int cc = 0; cc < 4; ++cc) {
                unsigned long long mk = __ballot(vals[rr * 4 + cc] != 0);
                if (l == 0)
                    *(unsigned long long*)&adjW[wv * 4 + rr][2 * (q * 4 + cc)] = mk;
            }
        __syncthreads();                        // staging q visible to all waves

        // ---- preload ALL 8 mask words of this group (2x ds_read_b128)
        uint4 shv0 = *(const uint4*)&adjW[m][q * 8];
        uint4 shv1 = *(const uint4*)&adjW[m][q * 8 + 4];
        if (q == 0) {
            dv_a = *(const uint4*)&dstH[g8];
            dv_b = *(const uint4*)&dstH[32 + g8];
        }

        // ---- issue group q+1 adj loads (hidden behind compute below)
        if (q < 7) {
            #pragma unroll
            for (int rr = 0; rr < 4; ++rr)
                #pragma unroll
                for (int cc = 0; cc < 4; ++cc)
                    vals[rr * 4 + cc] = adjBase[rr * N_ + (q + 1) * 256 + cc * 64];
        }

        // ---- compute 8 MFMA K-chunks of group q (j in [q*256, q*256+256))
        #pragma unroll
        for (int jj = 0; jj < 8; ++jj) {
            int it = q * 8 + jj;
            // prefetch chunk it+2 (tail overreads stay inside ws, never consumed)
            int fn = (it + 2) * 1024;
            short8 bf0_n = *(const short8*)&WhB[fn];
            short8 bf1_n = *(const short8*)&WhB[fn + 512];
            int j2 = ((it + 2) << 5) + g8;
            uint4  dv_n = *(const uint4*)&dstH[(j2 < N_) ? j2 : g8];

            unsigned sh = (jj < 4 ? ((const unsigned*)&shv0)[jj]
                                  : ((const unsigned*)&shv1)[jj - 4]) >> g8;
            const unsigned* du = (const unsigned*)&dv_a;
            __attribute__((aligned(16))) unsigned pk[4];
            #pragma unroll
            for (int c2 = 0; c2 < 4; ++c2) {
                half2v d2 = __builtin_bit_cast(half2v, du[c2]);
                half2v e2 = s2 + d2;                            // v_pk_add_f16
                half2v t2 = e2 * alf;                           // v_pk_mul_f16
                e2 = __builtin_elementwise_max(e2, t2);         // v_pk_max_f16 (lrelu)
                half2v x2;
                x2[0] = __ocml_exp2_f16(e2[0]);                 // v_exp_f16 x2
                x2[1] = __ocml_exp2_f16(e2[1]);
                unsigned mk = ((((sh >> (2 * c2 + 1)) & 1u) << 16)
                               | ((sh >> (2 * c2)) & 1u)) * 0x3C00u;  // {0,1} f16 pair
                x2 = x2 * __builtin_bit_cast(half2v, mk);       // v_pk_mul_f16 mask
                pk[c2] = __builtin_bit_cast(unsigned, x2);      // IS the A-frag pair
            }
            half8 af = __builtin_bit_cast(half8, *(uint4*)pk);
            acc0 = __builtin_amdgcn_mfma_f32_16x16x32_f16(
                       af, __builtin_bit_cast(half8, bf0_a), acc0, 0, 0, 0);
            acc1 = __builtin_amdgcn_mfma_f32_16x16x32_f16(
                       af, __builtin_bit_cast(half8, bf1_a), acc1, 0, 0, 0);
            acc2 = __builtin_amdgcn_mfma_f32_16x16x32_f16(af, ones, acc2, 0, 0, 0);
            // rotate depth-2 pipelines (fully unrolled -> pure renaming)
            bf0_a = bf0_b; bf0_b = bf0_n;
            bf1_a = bf1_b; bf1_b = bf1_n;
            dv_a = dv_b;   dv_b = dv_n;
        }
    }

    // in-register finalize: acc2 = full row sum (C/D: col=m, row=g*4+r)
    #pragma unroll
    for (int r = 0; r < 4; ++r) {
        float inv = 1.f / acc2[r];
        size_t o = ((size_t)b * N_ + i0 + g * 4 + r) * HD_ + h * 32 + m;
        out[o]      = acc0[r] * inv;
        out[o + 16] = acc1[r] * inv;
    }
}

extern "C" void kernel_launch(void* const* d_in, const int* in_sizes, int n_in,
                              void* d_out, int out_size, void* d_ws, size_t ws_size,
                              hipStream_t stream) {
    const float* h   = (const float*)d_in[0];
    const int*   adj = (const int*)d_in[1];
    const float* W   = (const float*)d_in[2];
    const float* a   = (const float*)d_in[3];
    float* out = (float*)d_out;

    unsigned short* WhF  = (unsigned short*)d_ws;
    float*          src  = (float*)((char*)d_ws + 4u * 1024 * 1024);
    unsigned short* dstb = (unsigned short*)((char*)d_ws + 4u * 1024 * 1024 + 256u * 1024);

    gat_prep4<<<B_ * (N_ / 32), 256, 0, stream>>>(h, W, a, WhF, src, dstb);
    gat_main14<<<B_ * (N_ / 16), 256, 0, stream>>>(adj, WhF, src, dstb, out);
}